// Round 4
// baseline (645.668 us; speedup 1.0000x reference)
//
#include <hip/hip_runtime.h>
#include <hip/hip_bf16.h>
#include <stdint.h>

#define M_DIM 4096   // B*S
#define K_DIM 2048   // H
#define N_DIM 8192   // OUT
#define NT 96        // K' = 3*2048 / 64

typedef __attribute__((ext_vector_type(4))) float f32x4;
typedef __attribute__((ext_vector_type(8))) __bf16 bf16x8;

typedef __attribute__((address_space(1))) const unsigned int g_u32_t;
typedef __attribute__((address_space(3))) unsigned int lds_u32_t;

static __device__ __forceinline__ void gload16(const void* g, void* l) {
  __builtin_amdgcn_global_load_lds((g_u32_t*)g, (lds_u32_t*)l, 16, 0, 0);
}

#define BOUNDF ((float)(-2.053748910631823))

__device__ __forceinline__ unsigned char gate_passed(float y1v, float sqv,
                                                     float sw, float sb) {
  float cm = y1v / 32.0f * sw + sb;
  float cv = (sqv / 32.0f - cm * cm) * sw * sw;
  float ts = cm / sqrtf(cv / 32.0f);
  return (ts < BOUNDF) ? (unsigned char)1 : (unsigned char)0;
}

// ---------------- split fp32 -> bf16 hi/lo, plus packed E-prefix copy ----------------
__global__ void split_bf16_kernel(const float* __restrict__ src,
                                  unsigned short* __restrict__ hi,
                                  unsigned short* __restrict__ lo,
                                  float* __restrict__ packed_e,
                                  int n4) {
  int i = blockIdx.x * blockDim.x + threadIdx.x;
  int stride = gridDim.x * blockDim.x;
  for (; i < n4; i += stride) {
    float4 v = reinterpret_cast<const float4*>(src)[i];
    int col4 = i & (K_DIM / 4 - 1);
    if (col4 < 8) {
      int row = i >> 9;
      reinterpret_cast<float4*>(packed_e)[row * 8 + col4] = v;
    }
    float xs[4] = {v.x, v.y, v.z, v.w};
    unsigned short hb[4], lb[4];
#pragma unroll
    for (int j = 0; j < 4; ++j) {
      __hip_bfloat16 t = __float2bfloat16(xs[j]);
      unsigned short tb = *reinterpret_cast<unsigned short*>(&t);
      float hf = __uint_as_float(((unsigned)tb) << 16);
      __hip_bfloat16 t2 = __float2bfloat16(xs[j] - hf);
      hb[j] = tb;
      lb[j] = *reinterpret_cast<unsigned short*>(&t2);
    }
    reinterpret_cast<ushort4*>(hi)[i] = make_ushort4(hb[0], hb[1], hb[2], hb[3]);
    reinterpret_cast<ushort4*>(lo)[i] = make_ushort4(lb[0], lb[1], lb[2], lb[3]);
  }
}

// ---------------- main GEMM: 256x256 tile, K'=6144, counted-vmcnt pipeline ----------------
// K' regions: t in [0,32): A=xh B=wh; [32,64): A=xh B=wl; [64,96): A=xl B=wh.
// LDS per buffer (64KB): [KH0: A 16K | B 16K][KH1: A 16K | B 16K]; 2 buffers = 128KB.
// Subtile layout within a 16KB panel: byte = (row>>3)*512 + ks*128 + (row&7)*16,
// ks = k-slot (8 bf16). Staged linearly (gload_lds), source pre-permuted per lane.

#define STAGE(TT, H, C)                                                        \
  {                                                                            \
    int rg_ = (TT) >> 5;                                                       \
    const unsigned short* As_ = (rg_ == 2) ? xl : xh;                          \
    const unsigned short* Bs_ = (rg_ == 1) ? wl : wh;                          \
    int kk0_ = (((TT) & 31) << 6) + ((H) << 5);                                \
    char* bse_ = smem + (C) * 65536 + (H) * 32768;                             \
    gload16(As_ + asrc0 + kk0_, bse_ + ldst);                                  \
    gload16(As_ + asrc1 + kk0_, bse_ + 8192 + ldst);                           \
    gload16(Bs_ + bsrc0 + kk0_, bse_ + 16384 + ldst);                          \
    gload16(Bs_ + bsrc1 + kk0_, bse_ + 24576 + ldst);                          \
  }

#define PHASE(CBASE, H)                                                        \
  {                                                                            \
    char* abp_ = smem + (CBASE) + (H) * 32768;                                 \
    bf16x8 af_[8];                                                             \
    bf16x8 bf_[4];                                                             \
    _Pragma("unroll") for (int m_ = 0; m_ < 8; ++m_)                           \
        af_[m_] = *reinterpret_cast<const bf16x8*>(abp_ + aoff_s + m_ * 1024); \
    _Pragma("unroll") for (int n_ = 0; n_ < 4; ++n_)                           \
        bf_[n_] = *reinterpret_cast<const bf16x8*>(abp_ + 16384 + boff_s + n_ * 1024); \
    __builtin_amdgcn_s_setprio(1);                                             \
    _Pragma("unroll") for (int m_ = 0; m_ < 8; ++m_)                           \
        _Pragma("unroll") for (int n_ = 0; n_ < 4; ++n_)                       \
            acc[m_][n_] = __builtin_amdgcn_mfma_f32_16x16x32_bf16(             \
                af_[m_], bf_[n_], acc[m_][n_], 0, 0, 0);                       \
    __builtin_amdgcn_s_setprio(0);                                             \
  }

__global__ __launch_bounds__(512, 2) void gemm8p_kernel(
    const unsigned short* __restrict__ xh, const unsigned short* __restrict__ xl,
    const unsigned short* __restrict__ wh, const unsigned short* __restrict__ wl,
    const float* __restrict__ xe_packed, const float* __restrict__ we_packed,
    const float* __restrict__ bias, const float* __restrict__ swp,
    const float* __restrict__ sbp, float* __restrict__ out) {
  __shared__ __align__(16) char smem[131072];

  // XCD-aware swizzle: 512 blocks % 8 == 0 -> bijective
  int bid = blockIdx.x;
  int sid = (bid & 7) * 64 + (bid >> 3);
  int bm = sid >> 5, bn = sid & 31;   // 16 x 32 tiles
  int row0 = bm * 256, col0 = bn * 256;

  int tid = threadIdx.x;
  int lane = tid & 63, w = tid >> 6;
  int wave_m = w >> 2, wave_n = w & 3;
  int cl = lane & 15, g = lane >> 4;

  // fragment LDS byte offsets (within a 16KB panel)
  int aoff_s = (wave_m * 16 + (cl >> 3)) * 512 + g * 128 + (cl & 7) * 16;
  int boff_s = (wave_n * 8 + (cl >> 3)) * 512 + g * 128 + (cl & 7) * 16;

  // staging geometry: LDS linear L = j*8192 + tid*16 within a panel.
  // row = (L>>9)*8 + ((L>>4)&7), ks = (L>>7)&3  -> source element (row, ks*8)
  int r0s = ((tid >> 5) << 3) | (tid & 7);   // j=0 row (0..127)
  int r1s = 128 + r0s;                        // j=1 row
  int kss = (tid >> 3) & 3;
  size_t asrc0 = (size_t)(row0 + r0s) * K_DIM + kss * 8;
  size_t asrc1 = (size_t)(row0 + r1s) * K_DIM + kss * 8;
  size_t bsrc0 = (size_t)(col0 + r0s) * K_DIM + kss * 8;
  size_t bsrc1 = (size_t)(col0 + r1s) * K_DIM + kss * 8;
  int ldst = tid * 16;

  f32x4 acc[8][4];
#pragma unroll
  for (int m = 0; m < 8; ++m)
#pragma unroll
    for (int n = 0; n < 4; ++n) acc[m][n] = (f32x4){0.f, 0.f, 0.f, 0.f};

  // ---- pipeline prologue: 12 loads/thread in flight ----
  STAGE(0, 0, 0);
  STAGE(0, 1, 0);
  STAGE(1, 0, 1);
  asm volatile("s_waitcnt vmcnt(8)" ::: "memory");   // KH0[0] landed
  __builtin_amdgcn_s_barrier();
  __builtin_amdgcn_sched_barrier(0);

#pragma unroll 1
  for (int t = 0; t < NT; ++t) {
    int cur = t & 1;
    int cbase = cur * 65536;
    // ---- phase A: compute k-half 0 of tile t; prefetch KH1[t+1] ----
    if (t + 1 < NT) STAGE(t + 1, 1, cur ^ 1);
    PHASE(cbase, 0);
    if (t <= NT - 2) {
      asm volatile("s_waitcnt vmcnt(8)" ::: "memory");  // KH1[t] landed
    } else {
      asm volatile("s_waitcnt vmcnt(0)" ::: "memory");  // tail
    }
    __builtin_amdgcn_s_barrier();
    __builtin_amdgcn_sched_barrier(0);
    // ---- phase B: compute k-half 1 of tile t; prefetch KH0[t+2] into freed buf ----
    if (t + 2 < NT) STAGE(t + 2, 0, cur);
    PHASE(cbase, 1);
    if (t < NT - 2) {
      asm volatile("s_waitcnt vmcnt(8)" ::: "memory");  // KH0[t+1] landed
    } else if (t == NT - 2) {
      asm volatile("s_waitcnt vmcnt(4)" ::: "memory");  // KH0[NT-1] landed
    }
    __builtin_amdgcn_s_barrier();
    __builtin_amdgcn_sched_barrier(0);
  }

  // ---- epilogue 1: store acc + bias (frees the accumulator registers) ----
  float bv[4];
#pragma unroll
  for (int n = 0; n < 4; ++n) bv[n] = bias[col0 + wave_n * 64 + n * 16 + cl];
#pragma unroll
  for (int m = 0; m < 8; ++m) {
    int rb = row0 + wave_m * 128 + m * 16 + g * 4;
#pragma unroll
    for (int n = 0; n < 4; ++n) {
      int c = col0 + wave_n * 64 + n * 16 + cl;
#pragma unroll
      for (int j = 0; j < 4; ++j)
        out[(size_t)(rb + j) * N_DIM + c] = acc[m][n][j] + bv[n];
    }
  }

  // ---- epilogue 2: exact-fp32 gate from packed E-prefixes; re-zero gated cells ----
  __syncthreads();
  float* xe_l = (float*)smem;              // [256][36]
  float* we_l = (float*)(smem + 36864);    // [256][36]
#pragma unroll
  for (int it = 0; it < 4; ++it) {
    int idx = it * 512 + tid;
    int r = idx >> 3, q = (idx & 7) * 4;
    *reinterpret_cast<float4*>(xe_l + r * 36 + q) =
        *reinterpret_cast<const float4*>(xe_packed + (size_t)(row0 + r) * 32 + q);
    *reinterpret_cast<float4*>(we_l + r * 36 + q) =
        *reinterpret_cast<const float4*>(we_packed + (size_t)(col0 + r) * 32 + q);
  }
  __syncthreads();
  float sw = *swp, sb = *sbp;

  f32x4 wev[4][8];
#pragma unroll
  for (int n = 0; n < 4; ++n) {
    int colw = wave_n * 64 + n * 16 + cl;
#pragma unroll
    for (int kq = 0; kq < 8; ++kq)
      wev[n][kq] = *reinterpret_cast<const f32x4*>(we_l + colw * 36 + kq * 4);
  }
#pragma unroll
  for (int m = 0; m < 8; ++m) {
#pragma unroll
    for (int j = 0; j < 4; ++j) {
      int rl = wave_m * 128 + m * 16 + g * 4 + j;
      f32x4 xev[8], xev2[8];
#pragma unroll
      for (int kq = 0; kq < 8; ++kq) {
        xev[kq] = *reinterpret_cast<const f32x4*>(xe_l + rl * 36 + kq * 4);
        xev2[kq] = xev[kq] * xev[kq];
      }
#pragma unroll
      for (int n = 0; n < 4; ++n) {
        float y1 = 0.0f, sqv = 0.0f;
#pragma unroll
        for (int kq = 0; kq < 8; ++kq)
#pragma unroll
          for (int kk = 0; kk < 4; ++kk) {
            float wv = wev[n][kq][kk];
            y1 = fmaf(xev[kq][kk], wv, y1);
            sqv = fmaf(xev2[kq][kk], wv * wv, sqv);
          }
        if (gate_passed(y1 + bv[n], sqv, sw, sb)) {
          int r = row0 + wave_m * 128 + m * 16 + g * 4 + j;
          int c = col0 + wave_n * 64 + n * 16 + cl;
          out[(size_t)r * N_DIM + c] = 0.0f;
        }
      }
    }
  }
}

// ---------------- fp32 fallback (only if ws_size too small) ----------------
__device__ __forceinline__ void stats4x4(const float* __restrict__ x,
                                         const float* __restrict__ w,
                                         int r0, int c0,
                                         float (&y1)[4][4], float (&sq)[4][4]) {
#pragma unroll
  for (int i = 0; i < 4; ++i)
#pragma unroll
    for (int j = 0; j < 4; ++j) { y1[i][j] = 0.0f; sq[i][j] = 0.0f; }
#pragma unroll
  for (int kc = 0; kc < 8; ++kc) {
    float4 xa[4], wa[4], x2[4], w2[4];
#pragma unroll
    for (int i = 0; i < 4; ++i)
      xa[i] = *reinterpret_cast<const float4*>(x + (size_t)(r0 + i) * K_DIM + kc * 4);
#pragma unroll
    for (int j = 0; j < 4; ++j)
      wa[j] = *reinterpret_cast<const float4*>(w + (size_t)(c0 + j) * K_DIM + kc * 4);
#pragma unroll
    for (int i = 0; i < 4; ++i)
      x2[i] = make_float4(xa[i].x * xa[i].x, xa[i].y * xa[i].y,
                          xa[i].z * xa[i].z, xa[i].w * xa[i].w);
#pragma unroll
    for (int j = 0; j < 4; ++j)
      w2[j] = make_float4(wa[j].x * wa[j].x, wa[j].y * wa[j].y,
                          wa[j].z * wa[j].z, wa[j].w * wa[j].w);
#pragma unroll
    for (int i = 0; i < 4; ++i)
#pragma unroll
      for (int j = 0; j < 4; ++j) {
        float a = y1[i][j];
        a = fmaf(xa[i].x, wa[j].x, a);
        a = fmaf(xa[i].y, wa[j].y, a);
        a = fmaf(xa[i].z, wa[j].z, a);
        a = fmaf(xa[i].w, wa[j].w, a);
        y1[i][j] = a;
        float b = sq[i][j];
        b = fmaf(x2[i].x, w2[j].x, b);
        b = fmaf(x2[i].y, w2[j].y, b);
        b = fmaf(x2[i].z, w2[j].z, b);
        b = fmaf(x2[i].w, w2[j].w, b);
        sq[i][j] = b;
      }
  }
}

__global__ void fallback_gemm_kernel(const float* __restrict__ x, const float* __restrict__ wgt,
                                     const float* __restrict__ bias, const float* __restrict__ swp,
                                     const float* __restrict__ sbp, float* __restrict__ out) {
  __shared__ float xs[64][36], ws2[64][36];
  int t = threadIdx.x;
  int tr = t >> 4, tc = t & 15;
  int r0 = blockIdx.x * 64, c0 = blockIdx.y * 64;
  float acc[4][4];
#pragma unroll
  for (int i = 0; i < 4; ++i)
#pragma unroll
    for (int j = 0; j < 4; ++j) acc[i][j] = 0.0f;

#pragma unroll 1
  for (int kt = 0; kt < K_DIM / 32; ++kt) {
#pragma unroll
    for (int i = 0; i < 2; ++i) {
      int idx = t + 256 * i;
      int row = idx >> 3;
      int kk = (idx & 7) * 4;
      *reinterpret_cast<float4*>(&xs[row][kk]) =
          *reinterpret_cast<const float4*>(x + (size_t)(r0 + row) * K_DIM + kt * 32 + kk);
      *reinterpret_cast<float4*>(&ws2[row][kk]) =
          *reinterpret_cast<const float4*>(wgt + (size_t)(c0 + row) * K_DIM + kt * 32 + kk);
    }
    __syncthreads();
#pragma unroll 4
    for (int k = 0; k < 32; ++k) {
      float xv[4], wv[4];
#pragma unroll
      for (int i = 0; i < 4; ++i) { xv[i] = xs[tr * 4 + i][k]; wv[i] = ws2[tc * 4 + i][k]; }
#pragma unroll
      for (int i = 0; i < 4; ++i)
#pragma unroll
        for (int j = 0; j < 4; ++j) acc[i][j] = fmaf(xv[i], wv[j], acc[i][j]);
    }
    __syncthreads();
  }

  float y1[4][4], sq[4][4];
  stats4x4(x, wgt, r0 + tr * 4, c0 + tc * 4, y1, sq);
  float sw = *swp, sb = *sbp;
#pragma unroll
  for (int i = 0; i < 4; ++i)
#pragma unroll
    for (int j = 0; j < 4; ++j) {
      int r = r0 + tr * 4 + i, c = c0 + tc * 4 + j;
      float bvv = bias[c];
      unsigned char p = gate_passed(y1[i][j] + bvv, sq[i][j], sw, sb);
      out[(size_t)r * N_DIM + c] = p ? 0.0f : (acc[i][j] + bvv);
    }
}

extern "C" void kernel_launch(void* const* d_in, const int* in_sizes, int n_in,
                              void* d_out, int out_size, void* d_ws, size_t ws_size,
                              hipStream_t stream) {
  (void)in_sizes; (void)n_in; (void)out_size;
  const float* x    = (const float*)d_in[0];
  const float* wgt  = (const float*)d_in[1];
  const float* bias = (const float*)d_in[2];
  const float* swp  = (const float*)d_in[3];
  const float* sbp  = (const float*)d_in[4];
  float* out = (float*)d_out;

  const size_t xh_off = 0;
  const size_t xl_off = xh_off + (size_t)M_DIM * K_DIM * 2;    // 16 MB
  const size_t wh_off = xl_off + (size_t)M_DIM * K_DIM * 2;    // 32 MB
  const size_t wl_off = wh_off + (size_t)N_DIM * K_DIM * 2;    // 64 MB
  const size_t xe_off = wl_off + (size_t)N_DIM * K_DIM * 2;    // 96 MB
  const size_t we_off = xe_off + (size_t)M_DIM * 32 * 4;       // +512 KB
  const size_t need   = we_off + (size_t)N_DIM * 32 * 4;       // +1 MB

  if (ws_size >= need) {
    unsigned short* xh = (unsigned short*)((char*)d_ws + xh_off);
    unsigned short* xl = (unsigned short*)((char*)d_ws + xl_off);
    unsigned short* wh = (unsigned short*)((char*)d_ws + wh_off);
    unsigned short* wl = (unsigned short*)((char*)d_ws + wl_off);
    float* xe = (float*)((char*)d_ws + xe_off);
    float* we = (float*)((char*)d_ws + we_off);

    hipLaunchKernelGGL(split_bf16_kernel, dim3(2048), dim3(256), 0, stream,
                       x, xh, xl, xe, M_DIM * K_DIM / 4);
    hipLaunchKernelGGL(split_bf16_kernel, dim3(2048), dim3(256), 0, stream,
                       wgt, wh, wl, we, N_DIM * K_DIM / 4);
    hipLaunchKernelGGL(gemm8p_kernel, dim3(512), dim3(512), 0, stream,
                       xh, xl, wh, wl, xe, we, bias, swp, sbp, out);
  } else {
    hipLaunchKernelGGL(fallback_gemm_kernel, dim3(M_DIM / 64, N_DIM / 64), dim3(256), 0, stream,
                       x, wgt, bias, swp, sbp, out);
  }
}